// Round 5
// baseline (188.792 us; speedup 1.0000x reference)
//
#include <hip/hip_runtime.h>
#include <hip/hip_bf16.h>
#include <cstdint>

#define SEQ   720
#define PRED  720
#define CH    862
#define NB    64
#define NIN   360   // IN_LEN
#define KP    384   // padded K (12 * 32)
#define PP    768   // padded pred (6 * 128)
#define BKK   32

typedef __attribute__((ext_vector_type(8))) short s16x8;
typedef __attribute__((ext_vector_type(4))) float f32x4;
typedef unsigned int u32;
typedef unsigned short u16;

__device__ __forceinline__ u16 to_bf16u(float f){
  __hip_bfloat16 h = __float2bfloat16(f);
  return *reinterpret_cast<u16*>(&h);
}

// ---------------- Kernel A: DCT-II ortho matrix D[n][m], n,m in [0,360) ----------------
__global__ __launch_bounds__(256) void k_dct(float* __restrict__ Dm){
  int idx = blockIdx.x*256 + threadIdx.x;
  if (idx >= NIN*NIN) return;
  int n = idx / NIN, m = idx % NIN;
  int r = ((2*m+1)*n) % (4*NIN);
  float ang = (float)r * (float)(3.14159265358979323846 / 720.0);
  float v = cosf(ang) * 0.07453559924999299f;   // sqrt(2/360)
  if (n == 0) v *= 0.7071067811865476f;
  Dm[idx] = v;
}

// ---------------- Kernel B: M[p][m] = (1/N) sum_n Wlo[p][n] * D[n][m]  (bf16) + row sums ----------------
__global__ __launch_bounds__(384) void k_mmat(const float* __restrict__ Wlo, const float* __restrict__ Dm,
                                              u16* __restrict__ Mbf, float* __restrict__ Srow,
                                              float* __restrict__ Slo){
  int p = blockIdx.x;
  int t = threadIdx.x;
  if (p >= PRED){
    Mbf[(size_t)p*KP + t] = 0;
    if (t == 0){ Srow[p] = 0.f; Slo[p] = 0.f; }
    return;
  }
  __shared__ float Wrow[NIN];
  __shared__ float redM[6], redW[6];
  if (t < NIN) Wrow[t] = Wlo[(size_t)p*NIN + t];
  __syncthreads();
  float acc = 0.f;
  if (t < NIN){
    const float* Dc = Dm + t;
    #pragma unroll 4
    for (int n = 0; n < NIN; n++) acc += Wrow[n] * Dc[(size_t)n*NIN];
    acc *= (1.0f/360.0f);
  }
  Mbf[(size_t)p*KP + t] = (t < NIN) ? to_bf16u(acc) : (u16)0;
  float mv = (t < NIN) ? acc : 0.f;
  float wv = (t < NIN) ? Wrow[t] : 0.f;
  #pragma unroll
  for (int off = 32; off > 0; off >>= 1){
    mv += __shfl_down(mv, off);
    wv += __shfl_down(wv, off);
  }
  int wid = t >> 6, lid = t & 63;
  if (lid == 0){ redM[wid] = mv; redW[wid] = wv; }
  __syncthreads();
  if (t == 0){
    float sm = 0.f, sw = 0.f;
    #pragma unroll
    for (int i = 0; i < 6; i++){ sm += redM[i]; sw += redW[i]; }
    Srow[p] = sm; Slo[p] = sw;
  }
}

// ---------------- Fused kernel: x -> pair-sum A panel (LDS) -> GEMM x M^T -> epilogue ----------------
// Block = (b, 64-channel tile). 512 threads (8 waves). 3 pt-chunks of 256 p.
// LDS: As 48KB (XOR-swizzled chunks) + 32KB union{build red/means, Bs dbuf, epilogue wbuf} = 80KB -> 2 blocks/CU.
#define GLOAD_LDS16(gp, lp_) __builtin_amdgcn_global_load_lds( \
    (const __attribute__((address_space(1))) u32*)(gp), \
    (__attribute__((address_space(3))) u32*)(lp_), 16, 0, 0)

__global__ __launch_bounds__(512, 4) void k_fused(
    const float* __restrict__ x, const u16* __restrict__ Mbf,
    const float* __restrict__ Srow, const float* __restrict__ Slo,
    const float* __restrict__ w1, const float* __restrict__ b1,
    const float* __restrict__ w2, const float* __restrict__ b2,
    const float* __restrict__ blo, float* __restrict__ out)
{
  int bid = blockIdx.x;
  int ct = bid % 14;
  int b  = bid / 14;
  int c0 = ct * 64;

  int t = threadIdx.x;
  int w = t >> 6, l = t & 63;

  __shared__ __align__(16) char smem[81920];
  u16* As = (u16*)smem;                                   // [64][384] u16, chunk-swizzled
  char* uni = smem + 49152;                               // 32 KB union
  u16* Bs0 = (u16*)uni;
  u16* Bs1 = (u16*)(uni + 16384);
  float (*red)[64]    = (float(*)[64])uni;                // build: [8][64]
  float* meansL       = (float*)(uni + 2048);             // build: [64]
  float (*wbuf)[8][68] = (float(*)[8][68])uni;            // epilogue: [8 waves][8][68]

  const float rs2 = 0.7071067811865476f;

  // ---- build phase: wave w covers m in [48w, 48w+48); lane l = c-local ----
  int cglob = c0 + l;
  bool cval = (cglob < CH);
  const float* xb = x + (size_t)b*SEQ*CH + cglob;
  float msum = 0.f;
  int mbase = 48 * w;
  #pragma unroll 1
  for (int i8 = 0; i8 < 6; i8++){
    u16 mb[8];
    #pragma unroll
    for (int j = 0; j < 8; j++){
      int m = mbase + i8*8 + j;
      float pr = 0.f;
      if (m < NIN && cval){
        size_t ro = (size_t)(2*m)*CH;
        pr = xb[ro] + xb[ro + CH];
      }
      msum += pr;
      mb[j] = to_bf16u(pr * rs2);
    }
    int ch   = (mbase >> 3) + i8;     // logical 8-k chunk 0..47
    int phys = ch ^ (l & 7);          // XOR swizzle (bijective within 8-chunk group)
    uint4 pk;
    pk.x = (u32)mb[0] | ((u32)mb[1] << 16);
    pk.y = (u32)mb[2] | ((u32)mb[3] << 16);
    pk.z = (u32)mb[4] | ((u32)mb[5] << 16);
    pk.w = (u32)mb[6] | ((u32)mb[7] << 16);
    *reinterpret_cast<uint4*>(As + (size_t)l*KP + phys*8) = pk;
  }
  red[w][l] = msum;
  __syncthreads();
  if (t < 64){
    float s = 0.f;
    #pragma unroll
    for (int ww = 0; ww < 8; ww++) s += red[ww][t];
    meansL[t] = s * (1.0f/SEQ);
  }
  __syncthreads();

  // ---- per-thread epilogue constants (c side) ----
  int cq = l & 15, pg = l >> 4;          // store mapping: 4 c per lane, 4 p-groups
  int cb4 = c0 + cq*4;
  float sc4[4], of4[4], cn4[4], bc4[4];
  #pragma unroll
  for (int j = 0; j < 4; j++){
    int c = cb4 + j;
    bool v = (c < CH);
    float w1v = v ? w1[c] : 0.f, w2v = v ? w2[c] : 0.f;
    float b1v = v ? b1[c] : 0.f, b2v = v ? b2[c] : 0.f;
    float mv = meansL[cq*4 + j];
    sc4[j] = 1.f + w1v*w2v;
    of4[j] = w1v*b2v + b1v;
    cn4[j] = mv;
    bc4[j] = 1.4142135623730951f * sc4[j] * mv;
  }
  bool cfull = (cb4 + 3 < CH);
  __syncthreads();   // red/means region now free for Bs

  // ---- GEMM phase ----
  int srow2 = t >> 2;                 // 0..127 (Bs stage row)
  int sq    = t & 3;
  int bperm = (srow2 >> 1) & 3;       // global-source pre-swizzle (R4-verified pair)
  int r16 = l & 15, kb = l >> 4;
  int rpermB = (r16 >> 1) & 3;        // Bs read-side XOR (matches bperm)
  size_t outb = (size_t)b*PRED*CH;

#define STAGE_B(dst, p0_, k0_) do { \
    GLOAD_LDS16(Mbf + (size_t)((p0_) + srow2)*KP + (k0_) + ((sq^bperm)*8),        (dst) + srow2*BKK + sq*8); \
    GLOAD_LDS16(Mbf + (size_t)((p0_) + 128 + srow2)*KP + (k0_) + ((sq^bperm)*8),  (dst) + (128+srow2)*BKK + sq*8); \
  } while(0)

  #pragma unroll 1
  for (int pt = 0; pt < 3; pt++){
    int p0 = pt * 256;
    // prefetch Srow/Slo/blo for this thread's 8 store-p's (hidden under K-loop)
    float spv[8], slv[8], blv[8];
    #pragma unroll
    for (int hq = 0; hq < 8; hq++){
      int p = p0 + w*32 + (hq>>2)*16 + ((hq>>1)&1)*8 + (hq&1)*4 + pg;
      p = (p < PRED) ? p : (PRED-1);
      spv[hq] = Srow[p]; slv[hq] = Slo[p]; blv[hq] = blo[p];
    }

    f32x4 acc[4][2] = {};
    STAGE_B(Bs0, p0, 0);
    #pragma unroll 1
    for (int ks = 0; ks < 12; ks++){
      u16* Bc = (ks & 1) ? Bs1 : Bs0;
      u16* Bn = (ks & 1) ? Bs0 : Bs1;
      if (ks < 11){
        STAGE_B(Bn, p0, (ks+1)*BKK);
        asm volatile("s_waitcnt vmcnt(2)" ::: "memory");
      } else {
        asm volatile("s_waitcnt vmcnt(0)" ::: "memory");
      }
      __builtin_amdgcn_s_barrier();
      s16x8 af[4], bfr[2];
      int ch0 = ks*4;
      #pragma unroll
      for (int mi = 0; mi < 4; mi++)
        af[mi] = *reinterpret_cast<const s16x8*>(As + (size_t)(mi*16 + r16)*KP + (((ch0 + kb) ^ (l & 7)))*8);
      #pragma unroll
      for (int ni = 0; ni < 2; ni++)
        bfr[ni] = *reinterpret_cast<const s16x8*>(Bc + (size_t)(w*32 + ni*16 + r16)*BKK + ((kb ^ rpermB))*8);
      __builtin_amdgcn_s_setprio(1);
      #pragma unroll
      for (int mi = 0; mi < 4; mi++)
        #pragma unroll
        for (int ni = 0; ni < 2; ni++)
          acc[mi][ni] = __builtin_amdgcn_mfma_f32_16x16x32_bf16(af[mi], bfr[ni], acc[mi][ni], 0, 0, 0);
      __builtin_amdgcn_s_setprio(0);
      __builtin_amdgcn_s_barrier();
    }
    __syncthreads();   // all Bs reads done -> wbuf may alias

    // epilogue: per wave, 32 p x 64 c; wbuf[w] = [8 p][68 c] per sub-pass
    #pragma unroll
    for (int ni = 0; ni < 2; ni++){
      #pragma unroll
      for (int half = 0; half < 2; half++){
        asm volatile("s_waitcnt lgkmcnt(0)" ::: "memory");
        if ((r16 >> 3) == half){
          #pragma unroll
          for (int mi = 0; mi < 4; mi++)
            #pragma unroll
            for (int r = 0; r < 4; r++)
              wbuf[w][r16 & 7][mi*16 + kb*4 + r] = acc[mi][ni][r];
        }
        asm volatile("s_waitcnt lgkmcnt(0)" ::: "memory");
        #pragma unroll
        for (int q = 0; q < 2; q++){
          int pi = q*4 + pg;                         // 0..7
          int p = p0 + w*32 + ni*16 + half*8 + pi;
          if (p < PRED && cb4 < CH){
            f32x4 g = *reinterpret_cast<const f32x4*>(&wbuf[w][pi][cq*4]);
            int hq = ni*4 + half*2 + q;
            float sp = spv[hq], sl = slv[hq], bl = blv[hq];
            f32x4 ov;
            #pragma unroll
            for (int j = 0; j < 4; j++)
              ov[j] = sc4[j]*g[j] + (cn4[j] - bc4[j]*sp + of4[j]*sl + bl);
            if (cfull){
              *reinterpret_cast<f32x4*>(&out[outb + (size_t)p*CH + cb4]) = ov;
            } else {
              #pragma unroll
              for (int j = 0; j < 4; j++)
                if (cb4 + j < CH) out[outb + (size_t)p*CH + cb4 + j] = ov[j];
            }
          }
        }
      }
    }
    __syncthreads();   // wbuf reads done before next pt's STAGE overwrites region
  }
}

extern "C" void kernel_launch(void* const* d_in, const int* in_sizes, int n_in,
                              void* d_out, int out_size, void* d_ws, size_t ws_size,
                              hipStream_t stream)
{
  const float* x   = (const float*)d_in[0];
  const float* w1  = (const float*)d_in[1];
  const float* b1  = (const float*)d_in[2];
  const float* w2  = (const float*)d_in[3];
  const float* b2  = (const float*)d_in[4];
  const float* Wlo = (const float*)d_in[5];
  const float* blo = (const float*)d_in[6];
  float* out = (float*)d_out;

  char* ws = (char*)d_ws;
  float* Dm    = (float*)(ws);
  u16*   Mbf   = (u16*)(ws + 518400);
  float* Srow  = (float*)(ws + 518400 + 589824);
  float* Slo   = (float*)(ws + 518400 + 589824 + 3072);

  k_dct<<<dim3((NIN*NIN + 255)/256), dim3(256), 0, stream>>>(Dm);
  k_mmat<<<dim3(PP), dim3(384), 0, stream>>>(Wlo, Dm, Mbf, Srow, Slo);
  k_fused<<<dim3(NB*14), dim3(512), 0, stream>>>(x, Mbf, Srow, Slo,
                                                 w1, b1, w2, b2, blo, out);
}